// Round 5
// baseline (477.535 us; speedup 1.0000x reference)
//
#include <hip/hip_runtime.h>
#include <stdint.h>

// Problem constants
#define MROWS 32768      // B*S = 8*4096
#define KD    256        // 2*DIM
#define VOCABN 8192

typedef _Float16 half8  __attribute__((ext_vector_type(8)));
typedef _Float16 half4v __attribute__((ext_vector_type(4)));
typedef float  floatx4  __attribute__((ext_vector_type(4)));

// scratch layout (byte offsets within d_ws; ws_size >= WS_NEED verified R3/R4)
#define A_OFF     0u          // (unused since R20: af loaded from gr/gi direct)
#define B_OFF     16777216u   // f16 cb [8192][256]   =  4,194,304 B
#define CN_OFF    20971520u   // f32 0.5*||c||^2 [8192] = 32,768 B
#define PART_OFF  21004288u   // float4 top2 [32768][8] = 4,194,304 B
#define IDX_OFF   25198592u   // int idx [32768] = 131,072 B
#define WS_NEED   25329664u

// ---- top-2 (max sigma) with smaller-index tie-break (flush/merge path) ----
struct Top2 { float s1; int i1; float s2; int i2; };

__device__ __forceinline__ bool better(float sa, int ia, float sb, int ib) {
    return (sa > sb) || (sa == sb && ia < ib);
}
__device__ __forceinline__ Top2 merge2(const Top2& a, const Top2& b) {
    Top2 r;
    if (better(b.s1, b.i1, a.s1, a.i1)) {
        r.s1 = b.s1; r.i1 = b.i1;
        if (better(a.s1, a.i1, b.s2, b.i2)) { r.s2 = a.s1; r.i2 = a.i1; }
        else                                { r.s2 = b.s2; r.i2 = b.i2; }
    } else {
        r.s1 = a.s1; r.i1 = a.i1;
        if (better(b.s1, b.i1, a.s2, a.i2)) { r.s2 = b.s1; r.i2 = b.i1; }
        else                                { r.s2 = a.s2; r.i2 = a.i2; }
    }
    return r;
}

// async global->LDS, 16 B per lane. LDS dest is WAVE-UNIFORM base + lane*16;
// global src is per-lane (swizzle is applied by pre-permuting the src).
__device__ __forceinline__ void gll16(const void* g, const void* l) {
    __builtin_amdgcn_global_load_lds(
        (const __attribute__((address_space(1))) void*)g,
        (__attribute__((address_space(3))) void*)l, 16, 0, 0);
}

// counted-vmcnt pipe barrier (T3/T4): drain to N outstanding, raw s_barrier.
// NEVER vmcnt(0) in the main loop; sched_barrier(0) pins reordering.
#define PIPE_SYNC(N) do {                                        \
    asm volatile("s_waitcnt vmcnt(" #N ")" ::: "memory");        \
    __builtin_amdgcn_s_barrier();                                \
    __builtin_amdgcn_sched_barrier(0);                           \
} while (0)

// ---- 1. codebook f16 [8192][256] + 0.5*||c||^2 fp32 ----
__global__ __launch_bounds__(64) void prep_c(const float* __restrict__ cb,
                                             _Float16* __restrict__ B,
                                             float* __restrict__ cnorm) {
    int v = blockIdx.x;
    int lane = threadIdx.x;                    // 0..63, 4 floats each
    float4 c = ((const float4*)(cb + (size_t)v * 256))[lane];
    half4v h;
    h[0] = (_Float16)c.x; h[1] = (_Float16)c.y;
    h[2] = (_Float16)c.z; h[3] = (_Float16)c.w;
    ((half4v*)(B + (size_t)v * 256))[lane] = h;
    float s = c.x * c.x + c.y * c.y + c.z * c.z + c.w * c.w;
    #pragma unroll
    for (int m = 32; m; m >>= 1) s += __shfl_xor(s, m);
    if (lane == 0) cnorm[v] = 0.5f * s;
}

// ---- 2. f16 GEMM + per-row top-2 argmax(sigma) ----
// R19 post-mortem: datapath restored (112 VGPR, 26 MB fetch, 0 conflicts,
// 297 us) but occupancy stayed 22.7% -- the GRID (512 blocks = 2/CU) was the
// cap, not LDS. R20: split vocab in half; block = 64 rows x 4096 cols (32 g),
// grid 1024 -> 3 blocks/CU (3 x 52 KB = 156 <= 160 KB LDS) = 12 waves/CU,
// 1.5x latency hiding, per-wave code identical. part slots [nh*4, nh*4+4).
// prep_z folded in: af loaded from gr/gi (f32) + converted in prologue
// (identical f32->f16 rounding), killing one launch + 64 MB A round-trip.
// Floors: MFMA 66 us (16x16 rate), LDS B-read 55 us, L2 staging 62 us.
__global__ __launch_bounds__(256) void gemm_argmin(const float* __restrict__ gr,
                                                   const float* __restrict__ gi,
                                                   const _Float16* __restrict__ B,
                                                   const float* __restrict__ cnorm,
                                                   float4* __restrict__ part) {
    // LDS: 3 x 16 KB slice buffers | 2 x 1 KB cnorm | 2 KB topbuf = 52 KB
    __shared__ __align__(16) char lds[53248];
    float4* topbuf = (float4*)(lds + 51200);

    const int tid = threadIdx.x;
    const int bid = blockIdx.x;
    const int nh  = bid & 1;                  // vocab half: g in [nh*32,nh*32+32)
    const int m0  = (bid >> 1) * 64;
    const int wave = tid >> 6, lane = tid & 63;
    const int wr = wave >> 1, wc = wave & 1;           // 2x2: 32 rows x 64 cols
    const int lane16 = lane & 15, quad = lane >> 4;

    // A-fragments: load f32 from gr/gi, convert to f16 in-register (prologue
    // only; same rounding as the old prep_z). row m0+wr*32+i*16+lane16,
    // k = s*64 + ks*32 + quad*8; k<128 -> gr, else gi.
    half8 af[2][4][2];   // [i][s(=h)][ks]
    #pragma unroll
    for (int i = 0; i < 2; ++i) {
        const int row = m0 + wr * 32 + i * 16 + lane16;
        const float* zr = gr + (size_t)row * 128 + quad * 8;
        const float* zi = gi + (size_t)row * 128 + quad * 8;
        #pragma unroll
        for (int s = 0; s < 4; ++s)
            #pragma unroll
            for (int ks = 0; ks < 2; ++ks) {
                const int kb = s * 64 + ks * 32;        // 0..224, static
                const float* p = (kb < 128) ? (zr + kb) : (zi + (kb - 128));
                float4 lo = *(const float4*)p;
                float4 hi = *(const float4*)(p + 4);
                half8 hf;
                hf[0] = (_Float16)lo.x; hf[1] = (_Float16)lo.y;
                hf[2] = (_Float16)lo.z; hf[3] = (_Float16)lo.w;
                hf[4] = (_Float16)hi.x; hf[5] = (_Float16)hi.y;
                hf[6] = (_Float16)hi.z; hf[7] = (_Float16)hi.w;
                af[i][s][ks] = hf;
            }
    }

    // ---- staging geometry (16-KB slice = [128 cols][128 B of k]) ----
    // Wave w stages cols [w*32,w*32+32) as 4 wave-loads of 1 KB (8 cols each).
    // Lane L -> col = colb + (L>>3), phys chunk L&7; fetches LOGICAL chunk
    // (L&7)^(L>>3), so the XOR'd reader sees B[col][k]. pbase pre-offset by
    // this block's vocab half (nh*32 g-groups = nh*1Mi f16).
    const int l3 = lane >> 3, l7 = lane & 7;
    const _Float16* pbase = B + (size_t)nh * 1048576
                          + (size_t)(wave * 32 + l3) * 256 + (l7 ^ l3) * 8;
    const uint32_t lwave = (uint32_t)wave * 4096;      // byte base in buffer

    // fragment ds_read offsets (bytes within a 16-KB buffer):
    // off(j,ks) = (wc*64+j*16+lane16)*128 + ((ks*4+quad) ^ (lane16&7))*16
    const uint32_t fr_base = (uint32_t)(wc * 64 + lane16) * 128;
    uint32_t cq[2];
    #pragma unroll
    for (int ks = 0; ks < 2; ++ks)
        cq[ks] = (uint32_t)(((ks * 4 + quad) ^ (lane16 & 7)) * 16);

    Top2 t2[2][4];
    #pragma unroll
    for (int i = 0; i < 2; ++i)
        #pragma unroll
        for (int r = 0; r < 4; ++r)
            t2[i][r] = Top2{-3.4e38f, 0x7fffffff, -3.4e38f, 0x7fffffff};

    // stage LOCAL slice v (v in [0,128), buffer b = v%3 compile-time at all
    // call sites). do_cn: wave0 stages cnorm for local g2 = v>>2 (global
    // g2+nh*32) into slot g2&1; rides the same vmcnt pipe, drained by the
    // following h==3 PIPE_SYNC before ACCINIT(g2) (R16-proven accounting).
    auto STAGE = [&](int v, int b, bool do_cn) {
        const _Float16* src = pbase + ((size_t)(v >> 2) << 15)
                            + (size_t)((v & 3) * 64);
        char* dst = lds + b * 16384 + lwave;
        #pragma unroll
        for (int q = 0; q < 4; ++q)
            gll16(src + q * 2048, dst + q * 1024);
        if (do_cn && wave == 0) {
            int g2 = v >> 2;                  // local
            gll16(cnorm + (size_t)(g2 + nh * 32) * 128 + (lane & 31) * 4,
                  lds + 49152 + (g2 & 1) * 1024);
        }
    };

    // compute k-chunk h of the current g from buffer b: 8 ds_read_b128 + 16 MFMA
    auto COMPUTE = [&](int b, int h, floatx4 (&acc)[2][4]) {
        const char* cur = lds + b * 16384;
        half8 bf[4][2];
        #pragma unroll
        for (int j = 0; j < 4; ++j)
            #pragma unroll
            for (int ks = 0; ks < 2; ++ks)
                bf[j][ks] = *(const half8*)(cur + fr_base + j * 2048 + cq[ks]);
        #pragma unroll
        for (int ks = 0; ks < 2; ++ks)
            #pragma unroll
            for (int i = 0; i < 2; ++i)
                #pragma unroll
                for (int j = 0; j < 4; ++j)
                    acc[i][j] = __builtin_amdgcn_mfma_f32_16x16x32_f16(
                        af[i][h][ks], bf[j][ks], acc[i][j], 0, 0, 0);
    };

    auto ACCINIT = [&](int g, floatx4 (&acc)[2][4]) {     // g local
        const float* cl = (const float*)(lds + 49152 + (g & 1) * 1024)
                          + wc * 64 + lane16;
        #pragma unroll
        for (int j = 0; j < 4; ++j) {
            float nh2 = -cl[j * 16];
            acc[0][j] = (floatx4){nh2, nh2, nh2, nh2};
            acc[1][j] = acc[0][j];
        }
    };

    // streaming top-2 (C/D layout: col=lane&15, row=quad*4+r). Cheap form;
    // exact ties deferred to resolve's fp64 refine. gG = GLOBAL g.
    auto TOP2 = [&](int gG, floatx4 (&acc)[2][4]) {
        const int colb = gG * 128 + wc * 64 + lane16;
        #pragma unroll
        for (int i = 0; i < 2; ++i)
            #pragma unroll
            for (int r = 0; r < 4; ++r) {
                Top2& t = t2[i][r];
                #pragma unroll
                for (int j = 0; j < 4; ++j) {
                    float sv = acc[i][j][r];
                    int col = colb + j * 16;
                    bool gt1 = sv > t.s1;
                    bool gt2 = sv > t.s2;
#if __has_builtin(__builtin_amdgcn_fmed3f)
                    float ns2 = __builtin_amdgcn_fmed3f(sv, t.s2, t.s1);
#else
                    float ns2 = gt1 ? t.s1 : (gt2 ? sv : t.s2);
#endif
                    t.i2 = gt1 ? t.i1 : (gt2 ? col : t.i2);
                    t.i1 = gt1 ? col : t.i1;
                    t.s1 = gt1 ? sv  : t.s1;
                    t.s2 = ns2;
                }
            }
    };

    // flush: 16-lane butterfly + cross-wave merge via topbuf + part write.
    // lgkm-only barriers -- staged loads stay in flight. slot is GLOBAL.
    auto FLUSH = [&](int slot) {
        #pragma unroll
        for (int i = 0; i < 2; ++i)
            #pragma unroll
            for (int r = 0; r < 4; ++r) {
                Top2 t = t2[i][r];
                #pragma unroll
                for (int m = 1; m < 16; m <<= 1) {
                    Top2 o;
                    o.s1 = __shfl_xor(t.s1, m); o.i1 = __shfl_xor(t.i1, m);
                    o.s2 = __shfl_xor(t.s2, m); o.i2 = __shfl_xor(t.i2, m);
                    t = merge2(t, o);
                }
                if (lane16 == 0) {
                    int rl = wr * 32 + i * 16 + quad * 4 + r;   // 0..63
                    topbuf[rl * 2 + wc] =
                        make_float4(t.s1, __int_as_float(t.i1),
                                    t.s2, __int_as_float(t.i2));
                }
                t2[i][r] = Top2{-3.4e38f, 0x7fffffff, -3.4e38f, 0x7fffffff};
            }
        asm volatile("s_waitcnt lgkmcnt(0)" ::: "memory");
        __builtin_amdgcn_s_barrier();
        __builtin_amdgcn_sched_barrier(0);
        if (tid < 64) {
            float4 e0 = topbuf[tid * 2 + 0], e1 = topbuf[tid * 2 + 1];
            Top2 a{e0.x, __float_as_int(e0.y), e0.z, __float_as_int(e0.w)};
            Top2 b{e1.x, __float_as_int(e1.y), e1.z, __float_as_int(e1.w)};
            Top2 t = merge2(a, b);
            part[(size_t)(m0 + tid) * 8 + slot] =
                make_float4(t.s1, __int_as_float(t.i1),
                            t.s2, __int_as_float(t.i2));
        }
        asm volatile("s_waitcnt lgkmcnt(0)" ::: "memory");
        __builtin_amdgcn_s_barrier();
        __builtin_amdgcn_sched_barrier(0);
    };

    // prologue: fill 2 pipeline stages; sync(4) drains af loads + slice 0 + cn
    STAGE(0, 0, true); STAGE(1, 1, false);
    PIPE_SYNC(4);

    // main loop: local g in triples so buf = (g*4+h)%3 = (gs+h)%3 is
    // compile-time. Per h: stage v+2 (depth-2), compute v, sync(4).
    for (int gg = 0; gg < 30; gg += 3) {
        #pragma unroll
        for (int gs = 0; gs < 3; ++gs) {
            const int g = gg + gs;
            floatx4 acc[2][4];
            ACCINIT(g, acc);
            #pragma unroll
            for (int h = 0; h < 4; ++h) {
                STAGE(g * 4 + h + 2, (gs + h + 2) % 3, h == 2);
                COMPUTE((gs + h) % 3, h, acc);
                PIPE_SYNC(4);
            }
            TOP2(g + nh * 32, acc);
            if ((g & 7) == 7) FLUSH((g >> 3) + nh * 4);
        }
    }
    {   // g = 30 (gs = 0): standard body, stages up to local slice 125
        floatx4 acc[2][4];
        ACCINIT(30, acc);
        #pragma unroll
        for (int h = 0; h < 4; ++h) {
            STAGE(122 + h, (h + 2) % 3, h == 2);   // 122..125 -> bufs 2,0,1,2
            COMPUTE(h % 3, h, acc);                // slices 120..123 -> 0,1,2,0
            PIPE_SYNC(4);
        }
        TOP2(30 + nh * 32, acc);
    }
    {   // g = 31 peeled (slices 124..127 -> bufs 1,2,0,1), descending drains
        floatx4 acc[2][4];
        ACCINIT(31, acc);
        STAGE(126, 0, false); COMPUTE(1, 0, acc); PIPE_SYNC(4);
        STAGE(127, 1, false); COMPUTE(2, 1, acc); PIPE_SYNC(4);
        COMPUTE(0, 2, acc);   PIPE_SYNC(0);
        COMPUTE(1, 3, acc);
        TOP2(31 + nh * 32, acc);
        FLUSH(3 + nh * 4);
    }
}

// ---- 3. resolve: merge 8 partials/row + WAVE-COOPERATIVE fp64 refine ----
// Compact (row,cand) pairs to LDS, one wave per candidate (64 lanes x 4 dims,
// fp64 shuffle-reduce), then each row scans its results. zero_vq folded in.
__global__ __launch_bounds__(256) void resolve(const float4* __restrict__ part,
                                               const float* __restrict__ gr,
                                               const float* __restrict__ gi,
                                               const float* __restrict__ cb,
                                               int* __restrict__ idx,
                                               float* __restrict__ out,
                                               size_t vq_off) {
    __shared__ int s_cnt;
    __shared__ int2 ent[2048];
    __shared__ double res[2048];

    const int tid = threadIdx.x;
    const int row = blockIdx.x * 256 + tid;   // grid 128
    if (blockIdx.x == 0 && tid == 0) out[vq_off] = 0.f;
    if (tid == 0) s_cnt = 0;

    float4 e[8];
    #pragma unroll
    for (int j = 0; j < 8; ++j) e[j] = part[(size_t)row * 8 + j];
    Top2 t{-3.4e38f, 0x7fffffff, -3.4e38f, 0x7fffffff};
    #pragma unroll
    for (int j = 0; j < 8; ++j) {
        Top2 o{e[j].x, __float_as_int(e[j].y), e[j].z, __float_as_int(e[j].w)};
        t = merge2(t, o);
    }
    int best = t.i1;
    const float MARGIN = 0.12f;   // ~7.7 sigma of f16-screen score-diff noise
    const float cut = t.s1 - MARGIN;
    const bool need = (t.s1 - t.s2 < MARGIN);
    __syncthreads();              // s_cnt initialized

    int nc = 0;
    if (need) {
        #pragma unroll
        for (int j = 0; j < 8; ++j)
            #pragma unroll
            for (int c = 0; c < 2; ++c) {
                float sv = c ? e[j].z : e[j].x;
                int   ci = __float_as_int(c ? e[j].w : e[j].y);
                nc += (sv >= cut && (unsigned)ci < 8192u) ? 1 : 0;
            }
    }
    int mybase = 0;
    bool serial = false;
    if (nc) {
        mybase = atomicAdd(&s_cnt, nc);
        if (mybase + nc <= 2048) {
            int k = 0;
            #pragma unroll
            for (int j = 0; j < 8; ++j)
                #pragma unroll
                for (int c = 0; c < 2; ++c) {
                    float sv = c ? e[j].z : e[j].x;
                    int   ci = __float_as_int(c ? e[j].w : e[j].y);
                    if (sv >= cut && (unsigned)ci < 8192u)
                        ent[mybase + (k++)] = make_int2(row, ci);
                }
        } else serial = true;     // overflow fallback (needs >8 cands/row avg)
    }
    __syncthreads();
    const int cnt = (s_cnt < 2048) ? s_cnt : 2048;
    const int wave = tid >> 6, lane = tid & 63;
    for (int ee = wave; ee < cnt; ee += 4) {
        int2 rc = ent[ee];
        float4 c4 = ((const float4*)(cb + (size_t)rc.y * 256))[lane];
        float4 z4 = (lane < 32)
                  ? ((const float4*)(gr + (size_t)rc.x * 128))[lane]
                  : ((const float4*)(gi + (size_t)rc.x * 128))[lane - 32];
        double dx = (double)z4.x - (double)c4.x;
        double dy = (double)z4.y - (double)c4.y;
        double dz = (double)z4.z - (double)c4.z;
        double dw = (double)z4.w - (double)c4.w;
        double d = dx * dx + dy * dy + dz * dz + dw * dw;
        #pragma unroll
        for (int m = 1; m < 64; m <<= 1) d += __shfl_xor(d, m);
        if (lane == 0) res[ee] = d;
    }
    __syncthreads();
    if (nc && !serial) {
        double bd = 1e300; int bi = 0x7fffffff;
        for (int k = 0; k < nc; ++k) {
            double d = res[mybase + k];
            int   ci = ent[mybase + k].y;
            if (d < bd || (d == bd && ci < bi)) { bd = d; bi = ci; }
        }
        if ((unsigned)bi < 8192u) best = bi;
    } else if (serial) {          // old proven serial path (rare)
        double bd = 1e300; int bi = 0x7fffffff;
        const float* zr = gr + (size_t)row * 128;
        const float* zi = gi + (size_t)row * 128;
        #pragma unroll
        for (int j = 0; j < 8; ++j)
            #pragma unroll
            for (int c = 0; c < 2; ++c) {
                float sv = c ? e[j].z : e[j].x;
                int   ci = __float_as_int(c ? e[j].w : e[j].y);
                if (sv >= cut && (unsigned)ci < 8192u) {
                    const float* crow = cb + (size_t)ci * 256;
                    double d = 0.0;
                    for (int k = 0; k < 128; ++k) {
                        double a = (double)zr[k] - (double)crow[k];
                        double b = (double)zi[k] - (double)crow[128 + k];
                        d += a * a + b * b;
                    }
                    if (d < bd || (d == bd && ci < bi)) { bd = d; bi = ci; }
                }
            }
        if ((unsigned)bi < 8192u) best = bi;
    }
    idx[row] = ((unsigned)best < 8192u) ? best : 0;
}

// ---- 4. gather + proposal(REAL part only) + salience + vq (one wave/row) ----
__global__ __launch_bounds__(256) void gather_epi(const int* __restrict__ idx,
                                                  const float* __restrict__ gr,
                                                  const float* __restrict__ gi,
                                                  const float* __restrict__ cb,
                                                  const float* __restrict__ salw,
                                                  const float* __restrict__ salb,
                                                  float* __restrict__ out,
                                                  size_t sal_off, size_t vq_off) {
    const int wave = threadIdx.x >> 6, lane = threadIdx.x & 63;
    const int row = blockIdx.x * 4 + wave;
    int id = idx[row];
    if ((unsigned)id >= 8192u) id = 0;   // clamp: no wild reads

    float4 c4 = ((const float4*)(cb + (size_t)id * 256))[lane];
    float4 z4 = (lane < 32) ? ((const float4*)(gr + (size_t)row * 128))[lane]
                            : ((const float4*)(gi + (size_t)row * 128))[lane - 32];

    float dx = c4.x - z4.x, dy = c4.y - z4.y, dz = c4.z - z4.z, dw = c4.w - z4.w;
    float vq = dx * dx + dy * dy + dz * dz + dw * dw;
    float4 w4 = ((const float4*)salw)[lane];
    float sal = c4.x * w4.x + c4.y * w4.y + c4.z * w4.z + c4.w * w4.w;
    #pragma unroll
    for (int m = 1; m < 64; m <<= 1) {
        vq  += __shfl_xor(vq, m);
        sal += __shfl_xor(sal, m);
    }

    // proposal: real part only — lanes 0..31 hold c[0..128) as float4s
    if (lane < 32 && (size_t)(row + 1) * 128 <= sal_off) {
        float4* op = (float4*)(out + (size_t)row * 128);
        op[lane] = c4;
    }
    if (lane == 0 && sal_off + row < vq_off)
        out[sal_off + row] = sal + salb[0];

    __shared__ float vqs[4];
    if (lane == 0) vqs[wave] = vq;
    __syncthreads();
    if (threadIdx.x == 0) {
        float p = (vqs[0] + vqs[1] + vqs[2] + vqs[3]) * (1.25f / 8388608.f);
        atomicAdd(out + vq_off, p);
    }
}

extern "C" void kernel_launch(void* const* d_in, const int* in_sizes, int n_in,
                              void* d_out, int out_size, void* d_ws, size_t ws_size,
                              hipStream_t stream) {
    const float* gr = (const float*)d_in[0];   // gw_real  [8,4096,128]
    const float* gi = (const float*)d_in[1];   // gw_imag  [8,4096,128]
    const float* cb = (const float*)d_in[2];   // codebook [8192,256]
    const float* sw = (const float*)d_in[3];   // sal_w    [1,256]
    const float* sb = (const float*)d_in[4];   // sal_b    [1]
    float* out = (float*)d_out;

    // Output offsets (out_size = 4,227,073 floats:
    // proposal-real 4,194,304 | salience 32,768 | vq_loss 1).
    size_t vq_off  = (size_t)out_size - 1;
    size_t sal_off = (size_t)out_size - 1 - 32768;

    char* base = (char*)d_ws;
    int*  idxb = (int*)(base + IDX_OFF);
    _Float16* Bq   = (_Float16*)(base + B_OFF);
    float*    cn   = (float*)   (base + CN_OFF);
    float4*   part = (float4*)  (base + PART_OFF);

    prep_c<<<8192, 64, 0, stream>>>(cb, Bq, cn);
    gemm_argmin<<<1024, 256, 0, stream>>>(gr, gi, Bq, cn, part);
    resolve<<<128, 256, 0, stream>>>(part, gr, gi, cb, idxb, out, vq_off);
    gather_epi<<<8192, 256, 0, stream>>>(idxb, gr, gi, cb, sw, sb, out,
                                         sal_off, vq_off);
}